// Round 2
// baseline (574.358 us; speedup 1.0000x reference)
//
#include <hip/hip_runtime.h>
#include <math.h>

#define EPS 1e-5f
#define NPASS 4        // source-index slices: 19.2MB/4 = 4.8MB ~ per-XCD L2

typedef __attribute__((ext_vector_type(8)))  _Float16 half8;   // 8 f16 (4 VGPR)
typedef __attribute__((ext_vector_type(16))) float    floatx16;
typedef __attribute__((ext_vector_type(4)))  int      iv4;

__device__ __forceinline__ unsigned short f2h_bits(float f) {
    _Float16 h = (_Float16)f;
    return __builtin_bit_cast(unsigned short, h);
}

// ---------------------------------------------------------------------------
// Fused prepass: one dispatch, block-range dispatch to roles.
//   blocks [0, nbData)                : data[N][32] fp32 -> dpk[N][32] f16
//   blocks [nbData, nbData+14)        : W[27][32][32] -> f16 B-fragments (wpk)
//   block   nbData+14                 : zero gs1/gs2/gcnt + zero dummy rows
//   blocks [nbData+15, ...)           : neigh[N][27] -> neighp[N][28]
// ---------------------------------------------------------------------------
__global__ __launch_bounds__(256) void pack_all_kernel(
    const float* __restrict__ data, unsigned short* __restrict__ dpk,
    const float* __restrict__ W, unsigned short* __restrict__ wpk,
    const int* __restrict__ neigh, int* __restrict__ neighp,
    float* __restrict__ gzero, int N, int nbData)
{
    const int b = blockIdx.x;
    const int tid = threadIdx.x;

    if (b < nbData) {
        const int i = b * 256 + tid;                 // float4 index
        if (i >= N * 8) return;
        const float4 v = ((const float4*)data)[i];
        ushort4 o;
        o.x = f2h_bits(v.x);
        o.y = f2h_bits(v.y);
        o.z = f2h_bits(v.z);
        o.w = f2h_bits(v.w);
        ((ushort4*)dpk)[i] = o;
        return;
    }
    const int wb = b - nbData;
    if (wb < 14) {
        // B[k][n]: lane l holds n=l&31, k=8*(l>>5)+j. Tap 27 = zeros.
        const int t = wb * 256 + tid;                // (tap*2+chunk)*64+lane
        const int l = t & 63;
        const int c = (t >> 6) & 1;
        const int k = t >> 7;
        ushort4 o0 = make_ushort4(0, 0, 0, 0), o1 = o0;
        if (k < 27) {
            const int n  = l & 31;
            const int cb = c * 16 + (l >> 5) * 8;    // ci base for this lane
            const float* wp = W + k * 1024 + n;
            o0.x = f2h_bits(wp[(cb + 0) * 32]);
            o0.y = f2h_bits(wp[(cb + 1) * 32]);
            o0.z = f2h_bits(wp[(cb + 2) * 32]);
            o0.w = f2h_bits(wp[(cb + 3) * 32]);
            o1.x = f2h_bits(wp[(cb + 4) * 32]);
            o1.y = f2h_bits(wp[(cb + 5) * 32]);
            o1.z = f2h_bits(wp[(cb + 6) * 32]);
            o1.w = f2h_bits(wp[(cb + 7) * 32]);
        }
        *(ushort4*)(wpk + (size_t)t * 8)     = o0;
        *(ushort4*)(wpk + (size_t)t * 8 + 4) = o1;
        return;
    }
    if (wb == 14) {
        if (tid < 520) gzero[tid] = 0.f;             // zero global stats
        // zero dummy rows N, N+1 (out-of-slice gathers land here -> MFMA +0)
        if (tid >= 192 && tid < 256) dpk[(size_t)N * 32 + (tid - 192)] = 0;
        return;
    }
    // neigh pack: [N][27] -> [N][28] (16 B-aligned rows for int4 loads)
    const int i = (wb - 15) * 256 + tid;
    if (i >= N * 28) return;
    const int n = i / 28;
    const int k = i % 28;
    neighp[i] = neigh[n * 27 + (k < 27 ? k : 26)];
}

// ---------------------------------------------------------------------------
// Deconv via f16 MFMA + GN stats, SOURCE-SLICED into NPASS passes.
// Round-1 evidence: 2x occupancy -> flat 3.8 TB/s => XCD<->LLC fabric wall on
// 518 MB of random 64B gathers over a 19.2 MB table (per-XCD L2 hit <=21%).
// Fix: pass p gathers only source rows in [p*ss,(p+1)*ss) (4.8 MB, ~L2-sized)
// so repeats hit L2; out-of-slice taps read a zeroed dummy row (index N, one
// hot line) via a single compare+select on the index -- no branches, chained
// acc stays correct. Neighbor indices live in 7 int4 regs across passes.
// Block = 512 = 8 waves; wave = 32 nodes x 32 couts; B staged in LDS (57 KB).
// ---------------------------------------------------------------------------
#define EFFI(i) ((((unsigned)((i) - base)) < uss) ? (i) : N)

#define LOADQ(d0,d1,d2,d3,d4,d5,d6,d7, nv) do {                              \
    const unsigned short* r0 = dpk + (size_t)EFFI((nv).x) * 32;              \
    const unsigned short* r1 = dpk + (size_t)EFFI((nv).y) * 32;              \
    const unsigned short* r2 = dpk + (size_t)EFFI((nv).z) * 32;              \
    const unsigned short* r3 = dpk + (size_t)EFFI((nv).w) * 32;              \
    d0 = *(const half8*)(r0 + aoff);  d1 = *(const half8*)(r0 + 16 + aoff);  \
    d2 = *(const half8*)(r1 + aoff);  d3 = *(const half8*)(r1 + 16 + aoff);  \
    d4 = *(const half8*)(r2 + aoff);  d5 = *(const half8*)(r2 + 16 + aoff);  \
    d6 = *(const half8*)(r3 + aoff);  d7 = *(const half8*)(r3 + 16 + aoff);  \
} while (0)

#define MFMAQ(iq, s0,s1,s2,s3,s4,s5,s6,s7) do {                              \
    acc = __builtin_amdgcn_mfma_f32_32x32x16_f16(s0, BL[(8*(iq)+0)*64 + l], acc, 0, 0, 0); \
    acc = __builtin_amdgcn_mfma_f32_32x32x16_f16(s1, BL[(8*(iq)+1)*64 + l], acc, 0, 0, 0); \
    acc = __builtin_amdgcn_mfma_f32_32x32x16_f16(s2, BL[(8*(iq)+2)*64 + l], acc, 0, 0, 0); \
    acc = __builtin_amdgcn_mfma_f32_32x32x16_f16(s3, BL[(8*(iq)+3)*64 + l], acc, 0, 0, 0); \
    acc = __builtin_amdgcn_mfma_f32_32x32x16_f16(s4, BL[(8*(iq)+4)*64 + l], acc, 0, 0, 0); \
    acc = __builtin_amdgcn_mfma_f32_32x32x16_f16(s5, BL[(8*(iq)+5)*64 + l], acc, 0, 0, 0); \
    acc = __builtin_amdgcn_mfma_f32_32x32x16_f16(s6, BL[(8*(iq)+6)*64 + l], acc, 0, 0, 0); \
    acc = __builtin_amdgcn_mfma_f32_32x32x16_f16(s7, BL[(8*(iq)+7)*64 + l], acc, 0, 0, 0); \
} while (0)

__global__ __launch_bounds__(512, 4) void deconv_stats_kernel(
    const unsigned short* __restrict__ dpk, const unsigned short* __restrict__ wpk,
    const int* __restrict__ nbase, int nstride, int quadok,
    const int* __restrict__ batch_id, float* __restrict__ out,
    float* __restrict__ gs1, float* __restrict__ gs2, float* __restrict__ gcnt,
    int N, int slice_sz)
{
    __shared__ unsigned short BW[28 * 2 * 64 * 8];    // 57344 B
    __shared__ float ls1[256];
    __shared__ float ls2[256];
    __shared__ float lcnt[8];

    const int t    = threadIdx.x;                     // 0..511
    const int wv   = t >> 6;                          // 0..7
    const int l    = t & 63;
    const int mrow = l & 31;
    const int half = l >> 5;
    const int wbase = blockIdx.x * 256 + wv * 32;
    const int node  = wbase + mrow;
    const int nc    = node < N ? node : N - 1;

    // stage all B fragments to LDS (coalesced, 7 x 8 KB with 512 threads)
#pragma unroll
    for (int r = 0; r < 7; ++r)
        ((int4*)BW)[r * 512 + t] = ((const int4*)wpk)[r * 512 + t];
    if (t < 256) {
        ls1[t] = 0.f;
        ls2[t] = 0.f;
    }
    if (t < 8) lcnt[t] = 0.f;
    __syncthreads();

    floatx16 acc;
#pragma unroll
    for (int r = 0; r < 16; ++r) acc[r] = 0.f;

    const int* nrow = nbase + (size_t)nc * nstride;
    const int aoff  = half * 8;      // f16 offset: chunk c base = 16c + 8*half

    // all 28 neighbor indices -> regs once (non-temporal: don't pollute L2)
    iv4 nq0, nq1, nq2, nq3, nq4, nq5, nq6;
    if (quadok) {
        const iv4* np = (const iv4*)nrow;
        nq0 = __builtin_nontemporal_load(np + 0);
        nq1 = __builtin_nontemporal_load(np + 1);
        nq2 = __builtin_nontemporal_load(np + 2);
        nq3 = __builtin_nontemporal_load(np + 3);
        nq4 = __builtin_nontemporal_load(np + 4);
        nq5 = __builtin_nontemporal_load(np + 5);
        nq6 = __builtin_nontemporal_load(np + 6);
    } else {
        nq0 = (iv4){nrow[0],  nrow[1],  nrow[2],  nrow[3]};
        nq1 = (iv4){nrow[4],  nrow[5],  nrow[6],  nrow[7]};
        nq2 = (iv4){nrow[8],  nrow[9],  nrow[10], nrow[11]};
        nq3 = (iv4){nrow[12], nrow[13], nrow[14], nrow[15]};
        nq4 = (iv4){nrow[16], nrow[17], nrow[18], nrow[19]};
        nq5 = (iv4){nrow[20], nrow[21], nrow[22], nrow[23]};
        nq6 = (iv4){nrow[24], nrow[25], nrow[26], nrow[26]};
    }

    const half8* BL = (const half8*)BW;
    const unsigned uss = (unsigned)slice_sz;

#pragma unroll 1
    for (int p = 0; p < NPASS; ++p) {
        const int base = p * slice_sz;
        half8 a0, a1, a2, a3, a4, a5, a6, a7;
        half8 b0, b1, b2, b3, b4, b5, b6, b7;
        // ping-pong one quad ahead (static names, no runtime-indexed arrays)
        LOADQ(a0,a1,a2,a3,a4,a5,a6,a7, nq0);
        LOADQ(b0,b1,b2,b3,b4,b5,b6,b7, nq1);
        MFMAQ(0, a0,a1,a2,a3,a4,a5,a6,a7);
        LOADQ(a0,a1,a2,a3,a4,a5,a6,a7, nq2);
        MFMAQ(1, b0,b1,b2,b3,b4,b5,b6,b7);
        LOADQ(b0,b1,b2,b3,b4,b5,b6,b7, nq3);
        MFMAQ(2, a0,a1,a2,a3,a4,a5,a6,a7);
        LOADQ(a0,a1,a2,a3,a4,a5,a6,a7, nq4);
        MFMAQ(3, b0,b1,b2,b3,b4,b5,b6,b7);
        LOADQ(b0,b1,b2,b3,b4,b5,b6,b7, nq5);
        MFMAQ(4, a0,a1,a2,a3,a4,a5,a6,a7);
        LOADQ(a0,a1,a2,a3,a4,a5,a6,a7, nq6);
        MFMAQ(5, b0,b1,b2,b3,b4,b5,b6,b7);
        MFMAQ(6, a0,a1,a2,a3,a4,a5,a6,a7);
    }

    // ---- epilogue (proven): C layout col=l&31, row=(r&3)+8(r>>2)+4*half
    // non-temporal stores: keep the 38 MB write from evicting the dpk slice
    const int co = mrow;
#pragma unroll
    for (int r = 0; r < 16; ++r) {
        const int row = (r & 3) + 8 * (r >> 2) + 4 * half;
        const int n = wbase + row;
        if (n < N) __builtin_nontemporal_store(acc[r], &out[(size_t)n * 32 + co]);
    }

    bool fast = (wbase + 31 < N);
    int bfst = 0;
    if (fast) {
        bfst = batch_id[wbase];
        fast = (bfst == batch_id[wbase + 31]);
    }
    if (fast) {
        float s1 = 0.f, s2 = 0.f;
#pragma unroll
        for (int r = 0; r < 16; ++r) {
            const float v = acc[r];
            s1 += v;
            s2 += v * v;
        }
        atomicAdd(&ls1[bfst * 32 + co], s1);
        atomicAdd(&ls2[bfst * 32 + co], s2);
    } else {
#pragma unroll
        for (int r = 0; r < 16; ++r) {
            const int row = (r & 3) + 8 * (r >> 2) + 4 * half;
            const int n = wbase + row;
            if (n < N) {
                const int b = batch_id[n];
                const float v = acc[r];
                atomicAdd(&ls1[b * 32 + co], v);
                atomicAdd(&ls2[b * 32 + co], v * v);
            }
        }
    }
    if (half == 0) {
        const int n = wbase + mrow;
        if (n < N) atomicAdd(&lcnt[batch_id[n]], 1.0f);
    }
    __syncthreads();

    if (t < 256) {
        float v;
        v = ls1[t]; if (v != 0.f) atomicAdd(&gs1[t], v);
        v = ls2[t]; if (v != 0.f) atomicAdd(&gs2[t], v);
        if (t < 8) { v = lcnt[t]; if (v != 0.f) atomicAdd(&gcnt[t], v); }
    }
}

// ---------------------------------------------------------------------------
// GN finalize + apply + ReLU (unchanged, proven)
// ---------------------------------------------------------------------------
__global__ __launch_bounds__(256) void gn_relu_kernel(
    float* __restrict__ out, const int* __restrict__ batch_id,
    const float* __restrict__ gs1, const float* __restrict__ gs2,
    const float* __restrict__ gcnt, const float* __restrict__ gamma,
    const float* __restrict__ beta, int N)
{
    const int idx = blockIdx.x * 256 + threadIdx.x;
    if (idx >= N * 8) return;
    const int n = idx >> 3;
    const int g = idx & 7;
    const int b = batch_id[n];

    const float cnt  = gcnt[b] * 4.0f;
    const float icnt = 1.0f / (cnt + EPS);
    const float4 s1 = *(const float4*)(gs1 + b * 32 + g * 4);
    const float4 s2 = *(const float4*)(gs2 + b * 32 + g * 4);
    const float S1 = s1.x + s1.y + s1.z + s1.w;
    const float S2 = s2.x + s2.y + s2.z + s2.w;
    const float m   = S1 * icnt;
    const float var = (S2 - 2.0f * m * S1 + cnt * m * m) * icnt;
    const float istd = rsqrtf(var + EPS);

    const float4 gm4 = *(const float4*)(gamma + g * 4);
    const float4 bt4 = *(const float4*)(beta + g * 4);
    float4 h = *(float4*)(out + (size_t)idx * 4);
    h.x = fmaxf((h.x - m) * istd * gm4.x + bt4.x, 0.f);
    h.y = fmaxf((h.y - m) * istd * gm4.y + bt4.y, 0.f);
    h.z = fmaxf((h.z - m) * istd * gm4.z + bt4.z, 0.f);
    h.w = fmaxf((h.w - m) * istd * gm4.w + bt4.w, 0.f);
    *(float4*)(out + (size_t)idx * 4) = h;
}

// ---------------------------------------------------------------------------
extern "C" void kernel_launch(void* const* d_in, const int* in_sizes, int n_in,
                              void* d_out, int out_size, void* d_ws, size_t ws_size,
                              hipStream_t stream) {
    const float* data     = (const float*)d_in[0];   // [N,32]
    const float* weights  = (const float*)d_in[1];   // [27,32,32]
    const float* gamma    = (const float*)d_in[2];   // [32]
    const float* beta     = (const float*)d_in[3];   // [32]
    const int*   neigh    = (const int*)d_in[4];     // [N,27]
    const int*   batch_id = (const int*)d_in[5];     // [N]
    const int N = in_sizes[0] / 32;
    float* out = (float*)d_out;

    // ws layout (bytes):
    //   [0, 2080)                 : gs1[256] gs2[256] gcnt[8]
    //   [4096, +(N+2)*64)         : dpk   (N x 32 f16 + 2 zeroed dummy rows)
    //   [.., +57344)              : wpk   (28*2*64 half8 fragments)
    //   [.., +N*112)              : neighp (N x 28 int)  -- only if ws fits
    char* wsb = (char*)d_ws;
    float* gs1  = (float*)wsb;
    float* gs2  = gs1 + 256;
    float* gcnt = gs1 + 512;
    const size_t dpk_bytes = ((size_t)N + 2) * 64;
    unsigned short* dpk = (unsigned short*)(wsb + 4096);
    unsigned short* wpk = (unsigned short*)(wsb + 4096 + dpk_bytes);
    int* neighp = (int*)(wsb + 4096 + dpk_bytes + 57344);

    const size_t need = 4096 + dpk_bytes + 57344 + (size_t)N * 112;
    const int pack_ok = (ws_size >= need) ? 1 : 0;

    // fused prepass: data pack + w pack + stats/dummy zero + neigh pack
    const int nbData  = (N * 8 + 255) / 256;
    const int nbNeigh = pack_ok ? (N * 28 + 255) / 256 : 0;
    hipLaunchKernelGGL(pack_all_kernel, dim3(nbData + 15 + nbNeigh), dim3(256),
                       0, stream, data, dpk, weights, wpk, neigh, neighp,
                       gs1, N, nbData);

    const int* nbase  = pack_ok ? neighp : neigh;
    const int nstride = pack_ok ? 28 : 27;

    const int slice_sz = (N + NPASS - 1) / NPASS;
    const int nblocks = (N + 255) / 256;
    hipLaunchKernelGGL(deconv_stats_kernel, dim3(nblocks), dim3(512), 0, stream,
                       dpk, wpk, nbase, nstride, pack_ok, batch_id, out,
                       gs1, gs2, gcnt, N, slice_sz);

    const int n8 = N * 8;
    hipLaunchKernelGGL(gn_relu_kernel, dim3((n8 + 255) / 256), dim3(256), 0,
                       stream, out, batch_id, gs1, gs2, gcnt, gamma, beta, N);
}

// Round 3
// 279.539 us; speedup vs baseline: 2.0547x; 2.0547x over previous
//
#include <hip/hip_runtime.h>
#include <math.h>

#define EPS 1e-5f

typedef __attribute__((ext_vector_type(8)))  _Float16 half8;   // 8 f16 (4 VGPR)
typedef __attribute__((ext_vector_type(16))) float    floatx16;

__device__ __forceinline__ unsigned short f2h_bits(float f) {
    _Float16 h = (_Float16)f;
    return __builtin_bit_cast(unsigned short, h);
}

// ---------------------------------------------------------------------------
// Fused prepass: one dispatch, block-range dispatch to roles.
//   blocks [0, nbData)                : data[N][32] fp32 -> dpk[N][32] f16
//   blocks [nbData, nbData+14)        : W[27][32][32] -> f16 B-fragments (wpk)
//   block   nbData+14                 : zero gs1/gs2/gcnt (520 floats)
//   blocks [nbData+15, ...)           : neigh[N][27] -> neighp[N][28]
// ---------------------------------------------------------------------------
__global__ __launch_bounds__(256) void pack_all_kernel(
    const float* __restrict__ data, unsigned short* __restrict__ dpk,
    const float* __restrict__ W, unsigned short* __restrict__ wpk,
    const int* __restrict__ neigh, int* __restrict__ neighp,
    float* __restrict__ gzero, int N, int nbData)
{
    const int b = blockIdx.x;
    const int tid = threadIdx.x;

    if (b < nbData) {
        const int i = b * 256 + tid;                 // float4 index
        if (i >= N * 8) return;
        const float4 v = ((const float4*)data)[i];
        ushort4 o;
        o.x = f2h_bits(v.x);
        o.y = f2h_bits(v.y);
        o.z = f2h_bits(v.z);
        o.w = f2h_bits(v.w);
        ((ushort4*)dpk)[i] = o;
        return;
    }
    const int wb = b - nbData;
    if (wb < 14) {
        // B[k][n]: lane l holds n=l&31, k=8*(l>>5)+j. Tap 27 = zeros.
        const int t = wb * 256 + tid;                // (tap*2+chunk)*64+lane
        const int l = t & 63;
        const int c = (t >> 6) & 1;
        const int k = t >> 7;
        ushort4 o0 = make_ushort4(0, 0, 0, 0), o1 = o0;
        if (k < 27) {
            const int n  = l & 31;
            const int cb = c * 16 + (l >> 5) * 8;    // ci base for this lane
            const float* wp = W + k * 1024 + n;
            o0.x = f2h_bits(wp[(cb + 0) * 32]);
            o0.y = f2h_bits(wp[(cb + 1) * 32]);
            o0.z = f2h_bits(wp[(cb + 2) * 32]);
            o0.w = f2h_bits(wp[(cb + 3) * 32]);
            o1.x = f2h_bits(wp[(cb + 4) * 32]);
            o1.y = f2h_bits(wp[(cb + 5) * 32]);
            o1.z = f2h_bits(wp[(cb + 6) * 32]);
            o1.w = f2h_bits(wp[(cb + 7) * 32]);
        }
        *(ushort4*)(wpk + (size_t)t * 8)     = o0;
        *(ushort4*)(wpk + (size_t)t * 8 + 4) = o1;
        return;
    }
    if (wb == 14) {
        if (tid < 520) gzero[tid] = 0.f;             // zero global stats
        return;
    }
    // neigh pack: [N][27] -> [N][28] (16 B-aligned rows for int4 loads)
    const int i = (wb - 15) * 256 + tid;
    if (i >= N * 28) return;
    const int n = i / 28;
    const int k = i % 28;
    neighp[i] = neigh[n * 27 + (k < 27 ? k : 26)];
}

// ---------------------------------------------------------------------------
// Deconv via f16 MFMA + GN stats. ROUND-0 PROVEN STRUCTURE (144.0 us), fully
// reverted from the round-2 slicing/NT experiment (FETCH 2.3x, WRITE 10x,
// 470 us -- mixed-generation blocks defeat temporal slicing; NT loads break
// intra-row spatial reuse; NT stores amplify partial-sector writes).
// Evidence across rounds 0-1: occupancy 20%->40% was null at ~3.8 TB/s =>
// fabric/LLC random-64B wall; floor ~= 506 MB / 3.8 ~= 133 us.
// This round's only change: write pre-GN activations as f16 (hraw, 19 MB)
// instead of f32 out (38 MB) -- halves deconv WRITE + gn_relu read, and
// reduces L2 write-allocate pollution of the dpk gather table.
// Block = 256 = 4 waves; wave = 32 nodes x 32 couts; B staged in LDS (57 KB).
// ---------------------------------------------------------------------------
__global__ __launch_bounds__(256) void deconv_stats_kernel(
    const unsigned short* __restrict__ dpk, const unsigned short* __restrict__ wpk,
    const int* __restrict__ nbase, int nstride, int quadok,
    const int* __restrict__ batch_id, float* __restrict__ out,
    unsigned short* __restrict__ hraw, int hok,
    float* __restrict__ gs1, float* __restrict__ gs2, float* __restrict__ gcnt,
    int N)
{
    __shared__ unsigned short BW[28 * 2 * 64 * 8];    // 57344 B
    __shared__ float ls1[256];
    __shared__ float ls2[256];
    __shared__ float lcnt[8];

    const int t    = threadIdx.x;
    const int wv   = t >> 6;
    const int l    = t & 63;
    const int mrow = l & 31;
    const int half = l >> 5;
    const int wbase = blockIdx.x * 128 + wv * 32;
    const int node  = wbase + mrow;
    const int nc    = node < N ? node : N - 1;

    // stage all B fragments to LDS (coalesced, 14 x 4 KB)
#pragma unroll
    for (int r = 0; r < 14; ++r)
        ((int4*)BW)[r * 256 + t] = ((const int4*)wpk)[r * 256 + t];
    ls1[t] = 0.f;
    ls2[t] = 0.f;
    if (t < 8) lcnt[t] = 0.f;
    __syncthreads();

    floatx16 acc;
#pragma unroll
    for (int r = 0; r < 16; ++r) acc[r] = 0.f;

    const int* nrow = nbase + (size_t)nc * nstride;
    const int aoff  = half * 8;      // f16 offset: chunk c base = 16c + 8*half

    int4 nq;
    if (quadok) nq = ((const int4*)nrow)[0];
    else { nq.x = nrow[0]; nq.y = nrow[1]; nq.z = nrow[2]; nq.w = nrow[3]; }

    half8 a0, a1, a2, a3, a4, a5, a6, a7;     // current quad: tap j, chunk c -> a(2j+c)
    {
        const unsigned short* r0 = dpk + (size_t)nq.x * 32;
        const unsigned short* r1 = dpk + (size_t)nq.y * 32;
        const unsigned short* r2 = dpk + (size_t)nq.z * 32;
        const unsigned short* r3 = dpk + (size_t)nq.w * 32;
        a0 = *(const half8*)(r0 + aoff);  a1 = *(const half8*)(r0 + 16 + aoff);
        a2 = *(const half8*)(r1 + aoff);  a3 = *(const half8*)(r1 + 16 + aoff);
        a4 = *(const half8*)(r2 + aoff);  a5 = *(const half8*)(r2 + 16 + aoff);
        a6 = *(const half8*)(r3 + aoff);  a7 = *(const half8*)(r3 + 16 + aoff);
    }

    const half8* BL = (const half8*)BW;

#pragma unroll 1
    for (int it = 0; it < 7; ++it) {
        half8 b0, b1, b2, b3, b4, b5, b6, b7;
        if (it < 6) {                 // issue next quad's gathers (latency cover)
            int4 nqn;
            if (quadok) nqn = ((const int4*)nrow)[it + 1];
            else {
                const int kb = (it + 1) * 4;
                nqn.x = nrow[kb];
                nqn.y = nrow[kb + 1];
                nqn.z = nrow[kb + 2];
                nqn.w = nrow[kb + 3 < 27 ? kb + 3 : 26];
            }
            const unsigned short* r0 = dpk + (size_t)nqn.x * 32;
            const unsigned short* r1 = dpk + (size_t)nqn.y * 32;
            const unsigned short* r2 = dpk + (size_t)nqn.z * 32;
            const unsigned short* r3 = dpk + (size_t)nqn.w * 32;
            b0 = *(const half8*)(r0 + aoff);  b1 = *(const half8*)(r0 + 16 + aoff);
            b2 = *(const half8*)(r1 + aoff);  b3 = *(const half8*)(r1 + 16 + aoff);
            b4 = *(const half8*)(r2 + aoff);  b5 = *(const half8*)(r2 + 16 + aoff);
            b6 = *(const half8*)(r3 + aoff);  b7 = *(const half8*)(r3 + 16 + aoff);
        }

        // compute current quad: (tap*2+chunk) = 8*it + (0..7) matches a0..a7
        acc = __builtin_amdgcn_mfma_f32_32x32x16_f16(a0, BL[(8 * it + 0) * 64 + l], acc, 0, 0, 0);
        acc = __builtin_amdgcn_mfma_f32_32x32x16_f16(a1, BL[(8 * it + 1) * 64 + l], acc, 0, 0, 0);
        acc = __builtin_amdgcn_mfma_f32_32x32x16_f16(a2, BL[(8 * it + 2) * 64 + l], acc, 0, 0, 0);
        acc = __builtin_amdgcn_mfma_f32_32x32x16_f16(a3, BL[(8 * it + 3) * 64 + l], acc, 0, 0, 0);
        acc = __builtin_amdgcn_mfma_f32_32x32x16_f16(a4, BL[(8 * it + 4) * 64 + l], acc, 0, 0, 0);
        acc = __builtin_amdgcn_mfma_f32_32x32x16_f16(a5, BL[(8 * it + 5) * 64 + l], acc, 0, 0, 0);
        acc = __builtin_amdgcn_mfma_f32_32x32x16_f16(a6, BL[(8 * it + 6) * 64 + l], acc, 0, 0, 0);
        acc = __builtin_amdgcn_mfma_f32_32x32x16_f16(a7, BL[(8 * it + 7) * 64 + l], acc, 0, 0, 0);

        if (it < 6) {
            a0 = b0; a1 = b1; a2 = b2; a3 = b3;
            a4 = b4; a5 = b5; a6 = b6; a7 = b7;
        }
    }

    // ---- epilogue (proven): C layout col=l&31, row=(r&3)+8(r>>2)+4*half
    // Pre-GN activations stored as f16 (hraw) when workspace allows: halves
    // the write traffic and the L2 pollution; f32 fallback otherwise.
    const int co = mrow;
    if (hok) {
#pragma unroll
        for (int r = 0; r < 16; ++r) {
            const int row = (r & 3) + 8 * (r >> 2) + 4 * half;
            const int n = wbase + row;
            if (n < N) hraw[(size_t)n * 32 + co] = f2h_bits(acc[r]);
        }
    } else {
#pragma unroll
        for (int r = 0; r < 16; ++r) {
            const int row = (r & 3) + 8 * (r >> 2) + 4 * half;
            const int n = wbase + row;
            if (n < N) out[(size_t)n * 32 + co] = acc[r];
        }
    }

    bool fast = (wbase + 31 < N);
    int bfst = 0;
    if (fast) {
        bfst = batch_id[wbase];
        fast = (bfst == batch_id[wbase + 31]);
    }
    if (fast) {
        float s1 = 0.f, s2 = 0.f;
#pragma unroll
        for (int r = 0; r < 16; ++r) {
            const float v = acc[r];
            s1 += v;
            s2 += v * v;
        }
        atomicAdd(&ls1[bfst * 32 + co], s1);
        atomicAdd(&ls2[bfst * 32 + co], s2);
    } else {
#pragma unroll
        for (int r = 0; r < 16; ++r) {
            const int row = (r & 3) + 8 * (r >> 2) + 4 * half;
            const int n = wbase + row;
            if (n < N) {
                const int b = batch_id[n];
                const float v = acc[r];
                atomicAdd(&ls1[b * 32 + co], v);
                atomicAdd(&ls2[b * 32 + co], v * v);
            }
        }
    }
    if (half == 0) {
        const int n = wbase + mrow;
        if (n < N) atomicAdd(&lcnt[batch_id[n]], 1.0f);
    }
    __syncthreads();

    {
        float v;
        v = ls1[t]; if (v != 0.f) atomicAdd(&gs1[t], v);
        v = ls2[t]; if (v != 0.f) atomicAdd(&gs2[t], v);
        if (t < 8) { v = lcnt[t]; if (v != 0.f) atomicAdd(&gcnt[t], v); }
    }
}

// ---------------------------------------------------------------------------
// GN finalize + apply + ReLU. Reads f16 hraw when available (halved input
// traffic), writes f32 out once.
// ---------------------------------------------------------------------------
__global__ __launch_bounds__(256) void gn_relu_kernel(
    float* __restrict__ out, const unsigned short* __restrict__ hraw, int hok,
    const int* __restrict__ batch_id,
    const float* __restrict__ gs1, const float* __restrict__ gs2,
    const float* __restrict__ gcnt, const float* __restrict__ gamma,
    const float* __restrict__ beta, int N)
{
    const int idx = blockIdx.x * 256 + threadIdx.x;
    if (idx >= N * 8) return;
    const int n = idx >> 3;
    const int g = idx & 7;
    const int b = batch_id[n];

    const float cnt  = gcnt[b] * 4.0f;
    const float icnt = 1.0f / (cnt + EPS);
    const float4 s1 = *(const float4*)(gs1 + b * 32 + g * 4);
    const float4 s2 = *(const float4*)(gs2 + b * 32 + g * 4);
    const float S1 = s1.x + s1.y + s1.z + s1.w;
    const float S2 = s2.x + s2.y + s2.z + s2.w;
    const float m   = S1 * icnt;
    const float var = (S2 - 2.0f * m * S1 + cnt * m * m) * icnt;
    const float istd = rsqrtf(var + EPS);

    const float4 gm4 = *(const float4*)(gamma + g * 4);
    const float4 bt4 = *(const float4*)(beta + g * 4);
    float4 h;
    if (hok) {
        const ushort4 hv = *(const ushort4*)(hraw + (size_t)idx * 4);
        h.x = (float)__builtin_bit_cast(_Float16, hv.x);
        h.y = (float)__builtin_bit_cast(_Float16, hv.y);
        h.z = (float)__builtin_bit_cast(_Float16, hv.z);
        h.w = (float)__builtin_bit_cast(_Float16, hv.w);
    } else {
        h = *(float4*)(out + (size_t)idx * 4);
    }
    h.x = fmaxf((h.x - m) * istd * gm4.x + bt4.x, 0.f);
    h.y = fmaxf((h.y - m) * istd * gm4.y + bt4.y, 0.f);
    h.z = fmaxf((h.z - m) * istd * gm4.z + bt4.z, 0.f);
    h.w = fmaxf((h.w - m) * istd * gm4.w + bt4.w, 0.f);
    *(float4*)(out + (size_t)idx * 4) = h;
}

// ---------------------------------------------------------------------------
extern "C" void kernel_launch(void* const* d_in, const int* in_sizes, int n_in,
                              void* d_out, int out_size, void* d_ws, size_t ws_size,
                              hipStream_t stream) {
    const float* data     = (const float*)d_in[0];   // [N,32]
    const float* weights  = (const float*)d_in[1];   // [27,32,32]
    const float* gamma    = (const float*)d_in[2];   // [32]
    const float* beta     = (const float*)d_in[3];   // [32]
    const int*   neigh    = (const int*)d_in[4];     // [N,27]
    const int*   batch_id = (const int*)d_in[5];     // [N]
    const int N = in_sizes[0] / 32;
    float* out = (float*)d_out;

    // ws layout (bytes):
    //   [0, 2080)                 : gs1[256] gs2[256] gcnt[8]
    //   [4096, +N*64)             : dpk   (N x 32 f16)
    //   [.., +57344)              : wpk   (28*2*64 half8 fragments)
    //   [.., +N*112)              : neighp (N x 28 int)   -- if ws fits
    //   [.., +N*64)               : hraw  (N x 32 f16)    -- if ws fits
    char* wsb = (char*)d_ws;
    float* gs1  = (float*)wsb;
    float* gs2  = gs1 + 256;
    float* gcnt = gs1 + 512;
    unsigned short* dpk = (unsigned short*)(wsb + 4096);
    unsigned short* wpk = (unsigned short*)(wsb + 4096 + (size_t)N * 64);
    int* neighp = (int*)(wsb + 4096 + (size_t)N * 64 + 57344);
    unsigned short* hraw = (unsigned short*)(wsb + 4096 + (size_t)N * 64 + 57344
                                             + (size_t)N * 112);

    const size_t need_np = 4096 + (size_t)N * 64 + 57344 + (size_t)N * 112;
    const size_t need_hr = need_np + (size_t)N * 64;
    const int pack_ok = (ws_size >= need_np) ? 1 : 0;
    const int hraw_ok = (ws_size >= need_hr) ? 1 : 0;

    // fused prepass: data pack + w pack + gs zero + (optional) neigh pack
    const int nbData  = (N * 8 + 255) / 256;
    const int nbNeigh = pack_ok ? (N * 28 + 255) / 256 : 0;
    hipLaunchKernelGGL(pack_all_kernel, dim3(nbData + 15 + nbNeigh), dim3(256),
                       0, stream, data, dpk, weights, wpk, neigh, neighp,
                       gs1, N, nbData);

    const int* nbase  = pack_ok ? neighp : neigh;
    const int nstride = pack_ok ? 28 : 27;

    const int nblocks = (N + 127) / 128;
    hipLaunchKernelGGL(deconv_stats_kernel, dim3(nblocks), dim3(256), 0, stream,
                       dpk, wpk, nbase, nstride, pack_ok, batch_id, out,
                       hraw, hraw_ok, gs1, gs2, gcnt, N);

    const int n8 = N * 8;
    hipLaunchKernelGGL(gn_relu_kernel, dim3((n8 + 255) / 256), dim3(256), 0,
                       stream, out, hraw, hraw_ok, batch_id,
                       gs1, gs2, gcnt, gamma, beta, N);
}

// Round 4
// 260.192 us; speedup vs baseline: 2.2074x; 1.0744x over previous
//
#include <hip/hip_runtime.h>
#include <math.h>

#define EPS 1e-5f

typedef __attribute__((ext_vector_type(8)))  _Float16 half8;   // 8 f16 (4 VGPR)
typedef __attribute__((ext_vector_type(16))) float    floatx16;

__device__ __forceinline__ unsigned short f2h_bits(float f) {
    _Float16 h = (_Float16)f;
    return __builtin_bit_cast(unsigned short, h);
}

// ---------------------------------------------------------------------------
// Fused prepass: one dispatch, block-range dispatch to roles.
//   blocks [0, nbData)       : data[N][32] fp32 -> dpk[N][32] f16
//   blocks [nbData, nbData+14): W[27][32][32] -> f16 B-fragments (wpk)
//   block   nbData+14        : zero gs1/gs2/gcnt (520 floats)
// (neighp repack DROPPED in round 4: it cost 67 MB of streaming + 33k blocks;
//  deconv's scalar index path reads neigh directly, same bytes, L1-resident.)
// ---------------------------------------------------------------------------
__global__ __launch_bounds__(256) void pack_all_kernel(
    const float* __restrict__ data, unsigned short* __restrict__ dpk,
    const float* __restrict__ W, unsigned short* __restrict__ wpk,
    float* __restrict__ gzero, int N, int nbData)
{
    const int b = blockIdx.x;
    const int tid = threadIdx.x;

    if (b < nbData) {
        const int i = b * 256 + tid;                 // float4 index
        if (i >= N * 8) return;
        const float4 v = ((const float4*)data)[i];
        ushort4 o;
        o.x = f2h_bits(v.x);
        o.y = f2h_bits(v.y);
        o.z = f2h_bits(v.z);
        o.w = f2h_bits(v.w);
        ((ushort4*)dpk)[i] = o;
        return;
    }
    const int wb = b - nbData;
    if (wb < 14) {
        // B[k][n]: lane l holds n=l&31, k=8*(l>>5)+j. Tap 27 = zeros.
        const int t = wb * 256 + tid;                // (tap*2+chunk)*64+lane
        const int l = t & 63;
        const int c = (t >> 6) & 1;
        const int k = t >> 7;
        ushort4 o0 = make_ushort4(0, 0, 0, 0), o1 = o0;
        if (k < 27) {
            const int n  = l & 31;
            const int cb = c * 16 + (l >> 5) * 8;    // ci base for this lane
            const float* wp = W + k * 1024 + n;
            o0.x = f2h_bits(wp[(cb + 0) * 32]);
            o0.y = f2h_bits(wp[(cb + 1) * 32]);
            o0.z = f2h_bits(wp[(cb + 2) * 32]);
            o0.w = f2h_bits(wp[(cb + 3) * 32]);
            o1.x = f2h_bits(wp[(cb + 4) * 32]);
            o1.y = f2h_bits(wp[(cb + 5) * 32]);
            o1.z = f2h_bits(wp[(cb + 6) * 32]);
            o1.w = f2h_bits(wp[(cb + 7) * 32]);
        }
        *(ushort4*)(wpk + (size_t)t * 8)     = o0;
        *(ushort4*)(wpk + (size_t)t * 8 + 4) = o1;
        return;
    }
    if (wb == 14) {
        if (tid < 520) gzero[tid] = 0.f;             // zero global stats
        return;
    }
}

// ---------------------------------------------------------------------------
// Deconv via f16 MFMA + GN stats. Round-0 proven structure + round-3 f16 hraw.
// Round-4: neighbor indices read DIRECTLY from neigh[N][27] with scalar loads
// (the proven quadok=0 path) -- a lane's 108 B index row stays L1-resident
// across its 7 quad-reads, so index traffic is unchanged while the prepass
// drops the 67 MB neighp repack.
// Evidence r0-r1: occupancy 20->40% null at ~3.5 TB/s => random-64B L2-fill
// wall; deconv floor ~= 487 MB / 3.5 ~= 139 us, we run at ~143.
// Block = 256 = 4 waves; wave = 32 nodes x 32 couts; B staged in LDS (57 KB).
// ---------------------------------------------------------------------------
__global__ __launch_bounds__(256) void deconv_stats_kernel(
    const unsigned short* __restrict__ dpk, const unsigned short* __restrict__ wpk,
    const int* __restrict__ neigh,
    const int* __restrict__ batch_id, float* __restrict__ out,
    unsigned short* __restrict__ hraw, int hok,
    float* __restrict__ gs1, float* __restrict__ gs2, float* __restrict__ gcnt,
    int N)
{
    __shared__ unsigned short BW[28 * 2 * 64 * 8];    // 57344 B
    __shared__ float ls1[256];
    __shared__ float ls2[256];
    __shared__ float lcnt[8];

    const int t    = threadIdx.x;
    const int wv   = t >> 6;
    const int l    = t & 63;
    const int mrow = l & 31;
    const int half = l >> 5;
    const int wbase = blockIdx.x * 128 + wv * 32;
    const int node  = wbase + mrow;
    const int nc    = node < N ? node : N - 1;

    // stage all B fragments to LDS (coalesced, 14 x 4 KB)
#pragma unroll
    for (int r = 0; r < 14; ++r)
        ((int4*)BW)[r * 256 + t] = ((const int4*)wpk)[r * 256 + t];
    ls1[t] = 0.f;
    ls2[t] = 0.f;
    if (t < 8) lcnt[t] = 0.f;
    __syncthreads();

    floatx16 acc;
#pragma unroll
    for (int r = 0; r < 16; ++r) acc[r] = 0.f;

    const int* nrow = neigh + (size_t)nc * 27;
    const int aoff  = half * 8;      // f16 offset: chunk c base = 16c + 8*half

    int4 nq;
    nq.x = nrow[0]; nq.y = nrow[1]; nq.z = nrow[2]; nq.w = nrow[3];

    half8 a0, a1, a2, a3, a4, a5, a6, a7;     // current quad: tap j, chunk c -> a(2j+c)
    {
        const unsigned short* r0 = dpk + (size_t)nq.x * 32;
        const unsigned short* r1 = dpk + (size_t)nq.y * 32;
        const unsigned short* r2 = dpk + (size_t)nq.z * 32;
        const unsigned short* r3 = dpk + (size_t)nq.w * 32;
        a0 = *(const half8*)(r0 + aoff);  a1 = *(const half8*)(r0 + 16 + aoff);
        a2 = *(const half8*)(r1 + aoff);  a3 = *(const half8*)(r1 + 16 + aoff);
        a4 = *(const half8*)(r2 + aoff);  a5 = *(const half8*)(r2 + 16 + aoff);
        a6 = *(const half8*)(r3 + aoff);  a7 = *(const half8*)(r3 + 16 + aoff);
    }

    const half8* BL = (const half8*)BW;

#pragma unroll 1
    for (int it = 0; it < 7; ++it) {
        half8 b0, b1, b2, b3, b4, b5, b6, b7;
        if (it < 6) {                 // issue next quad's gathers (latency cover)
            const int kb = (it + 1) * 4;
            int4 nqn;
            nqn.x = nrow[kb];
            nqn.y = nrow[kb + 1];
            nqn.z = nrow[kb + 2];
            nqn.w = nrow[kb + 3 < 27 ? kb + 3 : 26];
            const unsigned short* r0 = dpk + (size_t)nqn.x * 32;
            const unsigned short* r1 = dpk + (size_t)nqn.y * 32;
            const unsigned short* r2 = dpk + (size_t)nqn.z * 32;
            const unsigned short* r3 = dpk + (size_t)nqn.w * 32;
            b0 = *(const half8*)(r0 + aoff);  b1 = *(const half8*)(r0 + 16 + aoff);
            b2 = *(const half8*)(r1 + aoff);  b3 = *(const half8*)(r1 + 16 + aoff);
            b4 = *(const half8*)(r2 + aoff);  b5 = *(const half8*)(r2 + 16 + aoff);
            b6 = *(const half8*)(r3 + aoff);  b7 = *(const half8*)(r3 + 16 + aoff);
        }

        // compute current quad: (tap*2+chunk) = 8*it + (0..7) matches a0..a7
        acc = __builtin_amdgcn_mfma_f32_32x32x16_f16(a0, BL[(8 * it + 0) * 64 + l], acc, 0, 0, 0);
        acc = __builtin_amdgcn_mfma_f32_32x32x16_f16(a1, BL[(8 * it + 1) * 64 + l], acc, 0, 0, 0);
        acc = __builtin_amdgcn_mfma_f32_32x32x16_f16(a2, BL[(8 * it + 2) * 64 + l], acc, 0, 0, 0);
        acc = __builtin_amdgcn_mfma_f32_32x32x16_f16(a3, BL[(8 * it + 3) * 64 + l], acc, 0, 0, 0);
        acc = __builtin_amdgcn_mfma_f32_32x32x16_f16(a4, BL[(8 * it + 4) * 64 + l], acc, 0, 0, 0);
        acc = __builtin_amdgcn_mfma_f32_32x32x16_f16(a5, BL[(8 * it + 5) * 64 + l], acc, 0, 0, 0);
        acc = __builtin_amdgcn_mfma_f32_32x32x16_f16(a6, BL[(8 * it + 6) * 64 + l], acc, 0, 0, 0);
        acc = __builtin_amdgcn_mfma_f32_32x32x16_f16(a7, BL[(8 * it + 7) * 64 + l], acc, 0, 0, 0);

        if (it < 6) {
            a0 = b0; a1 = b1; a2 = b2; a3 = b3;
            a4 = b4; a5 = b5; a6 = b6; a7 = b7;
        }
    }

    // ---- epilogue (proven): C layout col=l&31, row=(r&3)+8(r>>2)+4*half
    // Pre-GN activations stored as f16 (hraw) when workspace allows: halves
    // the write traffic and the L2 pollution; f32 fallback otherwise.
    const int co = mrow;
    if (hok) {
#pragma unroll
        for (int r = 0; r < 16; ++r) {
            const int row = (r & 3) + 8 * (r >> 2) + 4 * half;
            const int n = wbase + row;
            if (n < N) hraw[(size_t)n * 32 + co] = f2h_bits(acc[r]);
        }
    } else {
#pragma unroll
        for (int r = 0; r < 16; ++r) {
            const int row = (r & 3) + 8 * (r >> 2) + 4 * half;
            const int n = wbase + row;
            if (n < N) out[(size_t)n * 32 + co] = acc[r];
        }
    }

    bool fast = (wbase + 31 < N);
    int bfst = 0;
    if (fast) {
        bfst = batch_id[wbase];
        fast = (bfst == batch_id[wbase + 31]);
    }
    if (fast) {
        float s1 = 0.f, s2 = 0.f;
#pragma unroll
        for (int r = 0; r < 16; ++r) {
            const float v = acc[r];
            s1 += v;
            s2 += v * v;
        }
        atomicAdd(&ls1[bfst * 32 + co], s1);
        atomicAdd(&ls2[bfst * 32 + co], s2);
    } else {
#pragma unroll
        for (int r = 0; r < 16; ++r) {
            const int row = (r & 3) + 8 * (r >> 2) + 4 * half;
            const int n = wbase + row;
            if (n < N) {
                const int b = batch_id[n];
                const float v = acc[r];
                atomicAdd(&ls1[b * 32 + co], v);
                atomicAdd(&ls2[b * 32 + co], v * v);
            }
        }
    }
    if (half == 0) {
        const int n = wbase + mrow;
        if (n < N) atomicAdd(&lcnt[batch_id[n]], 1.0f);
    }
    __syncthreads();

    {
        float v;
        v = ls1[t]; if (v != 0.f) atomicAdd(&gs1[t], v);
        v = ls2[t]; if (v != 0.f) atomicAdd(&gs2[t], v);
        if (t < 8) { v = lcnt[t]; if (v != 0.f) atomicAdd(&gcnt[t], v); }
    }
}

// ---------------------------------------------------------------------------
// GN finalize + apply + ReLU. Reads f16 hraw when available (halved input
// traffic), writes f32 out once.
// ---------------------------------------------------------------------------
__global__ __launch_bounds__(256) void gn_relu_kernel(
    float* __restrict__ out, const unsigned short* __restrict__ hraw, int hok,
    const int* __restrict__ batch_id,
    const float* __restrict__ gs1, const float* __restrict__ gs2,
    const float* __restrict__ gcnt, const float* __restrict__ gamma,
    const float* __restrict__ beta, int N)
{
    const int idx = blockIdx.x * 256 + threadIdx.x;
    if (idx >= N * 8) return;
    const int n = idx >> 3;
    const int g = idx & 7;
    const int b = batch_id[n];

    const float cnt  = gcnt[b] * 4.0f;
    const float icnt = 1.0f / (cnt + EPS);
    const float4 s1 = *(const float4*)(gs1 + b * 32 + g * 4);
    const float4 s2 = *(const float4*)(gs2 + b * 32 + g * 4);
    const float S1 = s1.x + s1.y + s1.z + s1.w;
    const float S2 = s2.x + s2.y + s2.z + s2.w;
    const float m   = S1 * icnt;
    const float var = (S2 - 2.0f * m * S1 + cnt * m * m) * icnt;
    const float istd = rsqrtf(var + EPS);

    const float4 gm4 = *(const float4*)(gamma + g * 4);
    const float4 bt4 = *(const float4*)(beta + g * 4);
    float4 h;
    if (hok) {
        const ushort4 hv = *(const ushort4*)(hraw + (size_t)idx * 4);
        h.x = (float)__builtin_bit_cast(_Float16, hv.x);
        h.y = (float)__builtin_bit_cast(_Float16, hv.y);
        h.z = (float)__builtin_bit_cast(_Float16, hv.z);
        h.w = (float)__builtin_bit_cast(_Float16, hv.w);
    } else {
        h = *(float4*)(out + (size_t)idx * 4);
    }
    h.x = fmaxf((h.x - m) * istd * gm4.x + bt4.x, 0.f);
    h.y = fmaxf((h.y - m) * istd * gm4.y + bt4.y, 0.f);
    h.z = fmaxf((h.z - m) * istd * gm4.z + bt4.z, 0.f);
    h.w = fmaxf((h.w - m) * istd * gm4.w + bt4.w, 0.f);
    *(float4*)(out + (size_t)idx * 4) = h;
}

// ---------------------------------------------------------------------------
extern "C" void kernel_launch(void* const* d_in, const int* in_sizes, int n_in,
                              void* d_out, int out_size, void* d_ws, size_t ws_size,
                              hipStream_t stream) {
    const float* data     = (const float*)d_in[0];   // [N,32]
    const float* weights  = (const float*)d_in[1];   // [27,32,32]
    const float* gamma    = (const float*)d_in[2];   // [32]
    const float* beta     = (const float*)d_in[3];   // [32]
    const int*   neigh    = (const int*)d_in[4];     // [N,27]
    const int*   batch_id = (const int*)d_in[5];     // [N]
    const int N = in_sizes[0] / 32;
    float* out = (float*)d_out;

    // ws layout (bytes):
    //   [0, 2080)                 : gs1[256] gs2[256] gcnt[8]
    //   [4096, +N*64)             : dpk   (N x 32 f16)
    //   [.., +57344)              : wpk   (28*2*64 half8 fragments)
    //   [.., +N*64)               : hraw  (N x 32 f16)    -- if ws fits
    char* wsb = (char*)d_ws;
    float* gs1  = (float*)wsb;
    float* gs2  = gs1 + 256;
    float* gcnt = gs1 + 512;
    unsigned short* dpk = (unsigned short*)(wsb + 4096);
    unsigned short* wpk = (unsigned short*)(wsb + 4096 + (size_t)N * 64);
    unsigned short* hraw = (unsigned short*)(wsb + 4096 + (size_t)N * 64 + 57344);

    const size_t need_hr = 4096 + (size_t)N * 64 + 57344 + (size_t)N * 64;
    const int hraw_ok = (ws_size >= need_hr) ? 1 : 0;

    // fused prepass: data pack + w pack + gs zero
    const int nbData = (N * 8 + 255) / 256;
    hipLaunchKernelGGL(pack_all_kernel, dim3(nbData + 15), dim3(256),
                       0, stream, data, dpk, weights, wpk, gs1, N, nbData);

    const int nblocks = (N + 127) / 128;
    hipLaunchKernelGGL(deconv_stats_kernel, dim3(nblocks), dim3(256), 0, stream,
                       dpk, wpk, neigh, batch_id, out,
                       hraw, hraw_ok, gs1, gs2, gcnt, N);

    const int n8 = N * 8;
    hipLaunchKernelGGL(gn_relu_kernel, dim3((n8 + 255) / 256), dim3(256), 0,
                       stream, out, hraw, hraw_ok, batch_id,
                       gs1, gs2, gcnt, gamma, beta, N);
}